// Round 5
// baseline (309.111 us; speedup 1.0000x reference)
//
#include <hip/hip_runtime.h>
#include <hip/hip_bf16.h>

// GCN: out = GCNConv2( relu( GCNConv1(x) ) )
// Round 4->5:
//  - bucketed 2-pass CSR build (old k_fill: 800K scattered 4B stores -> 52MB
//    HBM writes, 50us; new: clustered packed appends + per-bucket LDS sort)
//  - h stored pre-scaled: h'[i] = dinv[i]*h[i] (bf16) -> agg loop is pure gather-add
//  - agg gather unrolled x4 (old VGPR=16: single load in flight, latency-bound)

constexpr int NN = 50000;
constexpr int NE = 800000;
constexpr int DI = 96;
constexpr int DH = 96;
constexpr int DO = 48;

constexpr int BK_SHIFT = 6;                  // 64 dst nodes per bucket
constexpr int NBK      = (NN + 63) >> 6;     // 782 buckets, ~1023 edges each
constexpr int BK_CAP   = 2048;               // >> max bucket load (mean 1023, sd ~32)

typedef unsigned short ushort8 __attribute__((ext_vector_type(8)));

__device__ __forceinline__ float bf2f(unsigned short u) {
    return __uint_as_float(((unsigned int)u) << 16);
}

// ---------------- CSR build (bucketed) ----------------

__global__ void k_zero_int(int* __restrict__ p, int n) {
    int i = blockIdx.x * blockDim.x + threadIdx.x;
    if (i < n) p[i] = 0;
}

// per-block LDS histogram of buckets, flush with atomics
__global__ __launch_bounds__(256) void k_bcount(const int* __restrict__ dst,
                                                int* __restrict__ bcnt, int e) {
    __shared__ int hist[NBK];
    for (int i = threadIdx.x; i < NBK; i += 256) hist[i] = 0;
    __syncthreads();
    for (int i = blockIdx.x * blockDim.x + threadIdx.x; i < e; i += gridDim.x * blockDim.x)
        atomicAdd(&hist[dst[i] >> BK_SHIFT], 1);
    __syncthreads();
    for (int i = threadIdx.x; i < NBK; i += 256) {
        int v = hist[i];
        if (v) atomicAdd(&bcnt[i], v);
    }
}

// single block: exclusive scan of bucket counts -> bk_ptr, bk_cur
__global__ __launch_bounds__(1024) void k_scan_bk(const int* __restrict__ bcnt,
                                                  int* __restrict__ bk_ptr,
                                                  int* __restrict__ bk_cur,
                                                  int* __restrict__ row_ptr, int e) {
    __shared__ int sh[1024];
    const int t = threadIdx.x;
    const int v = (t < NBK) ? bcnt[t] : 0;
    sh[t] = v;
    __syncthreads();
#pragma unroll
    for (int off = 1; off < 1024; off <<= 1) {
        int x = sh[t];
        int a = (t >= off) ? sh[t - off] : 0;
        __syncthreads();
        sh[t] = x + a;
        __syncthreads();
    }
    if (t < NBK) {
        int excl = sh[t] - v;
        bk_ptr[t] = excl;
        bk_cur[t] = excl;
    }
    if (t == 0) {
        bk_ptr[NBK] = e;
        row_ptr[NN] = e;   // sentinel for agg
    }
}

// append packed (local_dst<<16)|src at the bucket frontier (clustered writes)
__global__ void k_append(const int* __restrict__ src, const int* __restrict__ dst,
                         int* __restrict__ bk_cur, unsigned* __restrict__ ebuf, int e) {
    int i = blockIdx.x * blockDim.x + threadIdx.x;
    if (i < e) {
        int d = dst[i];
        int b = d >> BK_SHIFT;
        int pos = atomicAdd(&bk_cur[b], 1);
        ebuf[pos] = ((unsigned)(d & 63) << 16) | (unsigned)src[i];  // NN < 65536
    }
}

// one block per bucket: LDS counting-sort by local dst; coalesced outputs
__global__ __launch_bounds__(256) void k_bsort(const unsigned* __restrict__ ebuf,
                                               const int* __restrict__ bk_ptr,
                                               int* __restrict__ row_ptr,
                                               float* __restrict__ dinv,
                                               int* __restrict__ src_sorted, int n) {
    __shared__ unsigned eL[BK_CAP];
    __shared__ int outL[BK_CAP];
    __shared__ int curL[64];
    __shared__ int baseL[64];

    const int b   = blockIdx.x;
    const int beg = bk_ptr[b];
    const int m   = bk_ptr[b + 1] - beg;   // <= BK_CAP for this distribution
    const int t   = threadIdx.x;

    if (t < 64) curL[t] = 0;
    __syncthreads();

    for (int i = t; i < m; i += 256) {
        unsigned v = ebuf[beg + i];
        eL[i] = v;
        atomicAdd(&curL[v >> 16], 1);      // per-local-dst count
    }
    __syncthreads();

    if (t < 64) {                          // wave 0: scan 64 counts
        int c = curL[t];
        int x = c;
#pragma unroll
        for (int off = 1; off < 64; off <<= 1) {
            int y = __shfl_up(x, off);
            if (t >= off) x += y;
        }
        int excl = x - c;
        baseL[t] = excl;
        int d0 = (b << BK_SHIFT) + t;
        if (d0 < n) {
            row_ptr[d0] = beg + excl;
            dinv[d0]    = rsqrtf((float)(c + 1));   // +1 self-loop
        }
    }
    __syncthreads();
    if (t < 64) curL[t] = baseL[t];        // -> cursors
    __syncthreads();

    for (int i = t; i < m; i += 256) {
        unsigned v = eL[i];
        int p = atomicAdd(&curL[v >> 16], 1);
        outL[p] = (int)(v & 0xFFFFu);
    }
    __syncthreads();
    for (int i = t; i < m; i += 256) src_sorted[beg + i] = outL[i];
}

// ---------------- dense GEMM: H[n] = bf16( dinv[row] * (X[n] @ W) ) ----------------

template<int DOUT>
__global__ __launch_bounds__(256) void k_gemm(const float* __restrict__ X,
                                              const float* __restrict__ W,
                                              const float* __restrict__ dinv,
                                              __hip_bfloat16* __restrict__ H, int n) {
    constexpr int ROWS = 32;
    constexpr int CPT  = DOUT / 16;
    constexpr int RPT  = 2;

    __shared__ float ws[DI * DOUT];
    __shared__ float xs[ROWS][DI];

    const int tid  = threadIdx.x;
    const int row0 = blockIdx.x * ROWS;

    for (int i = tid; i < DI * DOUT; i += 256) ws[i] = W[i];

    {
        const float4* Xv  = reinterpret_cast<const float4*>(X + (size_t)row0 * DI);
        float4*       xsv = reinterpret_cast<float4*>(&xs[0][0]);
        const int nv   = ROWS * DI / 4;
        const int maxv = ((n - row0) * DI) / 4;
        for (int i = tid; i < nv; i += 256) {
            float4 v = (i < maxv) ? Xv[i] : float4{0.f, 0.f, 0.f, 0.f};
            xsv[i] = v;
        }
    }
    __syncthreads();

    const int cg = tid & 15;
    const int rg = tid >> 4;

    float acc[RPT][CPT];
#pragma unroll
    for (int i = 0; i < RPT; ++i)
#pragma unroll
        for (int j = 0; j < CPT; ++j) acc[i][j] = 0.f;

    for (int k = 0; k < DI; ++k) {
        float xv[RPT];
#pragma unroll
        for (int i = 0; i < RPT; ++i) xv[i] = xs[rg * RPT + i][k];
#pragma unroll
        for (int j = 0; j < CPT; ++j) {
            float wv = ws[k * DOUT + cg * CPT + j];
#pragma unroll
            for (int i = 0; i < RPT; ++i) acc[i][j] += xv[i] * wv;
        }
    }

#pragma unroll
    for (int i = 0; i < RPT; ++i) {
        int row = row0 + rg * RPT + i;
        if (row < n) {
            float dv = dinv[row];
#pragma unroll
            for (int j = 0; j < CPT; ++j)
                H[(size_t)row * DOUT + cg * CPT + j] = __float2bfloat16(acc[i][j] * dv);
        }
    }
}

// ---------------- CSR aggregation over pre-scaled bf16 h' ----------------
// out[d] = dinv[d] * ( h'[d] + sum_{s in N(d)} h'[s] ) + bias ;  h' = dinv*h

template<int D, bool RELU>
__global__ __launch_bounds__(256) void k_agg_csr(const unsigned short* __restrict__ h,
                                                 const float* __restrict__ dinv,
                                                 const int* __restrict__ row_ptr,
                                                 const int* __restrict__ src_sorted,
                                                 const float* __restrict__ bias,
                                                 float* __restrict__ out, int n) {
    constexpr int G = D / 8;
    int t = blockIdx.x * blockDim.x + threadIdx.x;
    if (t >= n * G) return;
    const int node = t / G;
    const int g    = t % G;

    const ushort8* h8 = reinterpret_cast<const ushort8*>(h);

    float accA[8], accB[8];
    {
        ushort8 hv = h8[(size_t)node * G + g];   // self term h'[node]
#pragma unroll
        for (int j = 0; j < 8; ++j) { accA[j] = bf2f(hv[j]); accB[j] = 0.f; }
    }

    const int beg = row_ptr[node];
    const int end = row_ptr[node + 1];
    int k = beg;
    for (; k + 4 <= end; k += 4) {
        int s0 = src_sorted[k + 0];
        int s1 = src_sorted[k + 1];
        int s2 = src_sorted[k + 2];
        int s3 = src_sorted[k + 3];
        ushort8 v0 = h8[(size_t)s0 * G + g];
        ushort8 v1 = h8[(size_t)s1 * G + g];
        ushort8 v2 = h8[(size_t)s2 * G + g];
        ushort8 v3 = h8[(size_t)s3 * G + g];
#pragma unroll
        for (int j = 0; j < 8; ++j) {
            accA[j] += bf2f(v0[j]) + bf2f(v1[j]);
            accB[j] += bf2f(v2[j]) + bf2f(v3[j]);
        }
    }
    for (; k < end; ++k) {
        int s = src_sorted[k];
        ushort8 v = h8[(size_t)s * G + g];
#pragma unroll
        for (int j = 0; j < 8; ++j) accA[j] += bf2f(v[j]);
    }

    const float di = dinv[node];
    const float4* b4 = reinterpret_cast<const float4*>(bias);
    float4 b0 = b4[g * 2], b1 = b4[g * 2 + 1];
    float r[8];
#pragma unroll
    for (int j = 0; j < 8; ++j) r[j] = di * (accA[j] + accB[j]);
    r[0] += b0.x; r[1] += b0.y; r[2] += b0.z; r[3] += b0.w;
    r[4] += b1.x; r[5] += b1.y; r[6] += b1.z; r[7] += b1.w;
    if (RELU) {
#pragma unroll
        for (int j = 0; j < 8; ++j) r[j] = fmaxf(r[j], 0.f);
    }
    float4* o4 = reinterpret_cast<float4*>(out + (size_t)node * D + g * 8);
    o4[0] = float4{r[0], r[1], r[2], r[3]};
    o4[1] = float4{r[4], r[5], r[6], r[7]};
}

// ---------------- launch ----------------

extern "C" void kernel_launch(void* const* d_in, const int* in_sizes, int n_in,
                              void* d_out, int out_size, void* d_ws, size_t ws_size,
                              hipStream_t stream) {
    const float* x   = (const float*)d_in[0];
    const int*   ei  = (const int*)d_in[1];   // [2][NE] int32
    const float* W1  = (const float*)d_in[2];
    const float* b1  = (const float*)d_in[3];
    const float* W2  = (const float*)d_in[4];
    const float* b2  = (const float*)d_in[5];
    float*       out = (float*)d_out;

    const int* srcv = ei;
    const int* dstv = ei + NE;

    // workspace layout (16B alignment preserved for float4/ushort8 arrays)
    char* p = (char*)d_ws;
    float*          dinv  = (float*)p;          p += (size_t)NN * 4;            // 200000 (16B mult.)
    float*          a1    = (float*)p;          p += (size_t)NN * DH * 4;
    __hip_bfloat16* h1    = (__hip_bfloat16*)p; p += (size_t)NN * DH * 2;       // reused as h2
    int*      row_ptr     = (int*)p;            p += (size_t)(NN + 1) * 4;
    int*      src_sorted  = (int*)p;            p += (size_t)NE * 4;
    unsigned* ebuf        = (unsigned*)p;       p += (size_t)NE * 4;
    int*      bcnt        = (int*)p;            p += (size_t)NBK * 4;
    int*      bk_ptr      = (int*)p;            p += (size_t)(NBK + 1) * 4;
    int*      bk_cur      = (int*)p;            p += (size_t)NBK * 4;

    const int B = 256;

    // CSR build
    k_zero_int<<<(NBK + B - 1) / B, B, 0, stream>>>(bcnt, NBK);
    k_bcount<<<128, B, 0, stream>>>(dstv, bcnt, NE);
    k_scan_bk<<<1, 1024, 0, stream>>>(bcnt, bk_ptr, bk_cur, row_ptr, NE);
    k_append<<<(NE + B - 1) / B, B, 0, stream>>>(srcv, dstv, bk_cur, ebuf, NE);
    k_bsort<<<NBK, B, 0, stream>>>(ebuf, bk_ptr, row_ptr, dinv, src_sorted, NN);

    // layer 1: h1 = bf16(dinv * (x@W1)) ; a1 = relu(dinv*(self+gather) + b1)
    k_gemm<DH><<<(NN + 31) / 32, B, 0, stream>>>(x, W1, dinv, h1, NN);
    {
        int total = NN * (DH / 8);
        k_agg_csr<DH, true><<<(total + B - 1) / B, B, 0, stream>>>(
            (const unsigned short*)h1, dinv, row_ptr, src_sorted, b1, a1, NN);
    }

    // layer 2
    __hip_bfloat16* h2 = h1;
    k_gemm<DO><<<(NN + 31) / 32, B, 0, stream>>>(a1, W2, dinv, h2, NN);
    {
        int total = NN * (DO / 8);
        k_agg_csr<DO, false><<<(total + B - 1) / B, B, 0, stream>>>(
            (const unsigned short*)h2, dinv, row_ptr, src_sorted, b2, out, NN);
    }
}

// Round 6
// 129.857 us; speedup vs baseline: 2.3804x; 2.3804x over previous
//
#include <hip/hip_runtime.h>
#include <hip/hip_bf16.h>

// GCN: out = GCNConv2( relu( GCNConv1(x) ) )
// Round 5->6: atomic-free bucketing (multisplit). Round 5's k_append had 782
// global cursors x ~1023-deep atomic chains = 192us of pure same-address
// atomic serialization. Now: per-(block,bucket) counts matrix + scans give
// every edge a precomputed slot; scatter uses LDS cursors only.

constexpr int NN = 50000;
constexpr int NE = 800000;
constexpr int DI = 96;
constexpr int DH = 96;
constexpr int DO = 48;

constexpr int BK_SHIFT = 6;                  // 64 dst nodes per bucket
constexpr int NBK      = (NN + 63) >> 6;     // 782 buckets, ~1023 edges each
constexpr int BK_CAP   = 2048;               // >> max bucket load

constexpr int NCHUNK = 128;                  // blocks in hist/scatter
constexpr int CH     = (NE + NCHUNK - 1) / NCHUNK;  // 6250 edges per chunk

typedef unsigned short ushort8 __attribute__((ext_vector_type(8)));

__device__ __forceinline__ float bf2f(unsigned short u) {
    return __uint_as_float(((unsigned int)u) << 16);
}

// ---------------- CSR build (atomic-free multisplit) ----------------

// per-chunk LDS histogram -> transposed counts C[bucket][chunk]
__global__ __launch_bounds__(256) void k_hist(const int* __restrict__ dst,
                                              int* __restrict__ C, int e) {
    __shared__ int hist[NBK];
    for (int i = threadIdx.x; i < NBK; i += 256) hist[i] = 0;
    __syncthreads();
    const int blk = blockIdx.x;
    const int beg = blk * CH, end = min(beg + CH, e);
    for (int i = beg + threadIdx.x; i < end; i += 256)
        atomicAdd(&hist[dst[i] >> BK_SHIFT], 1);
    __syncthreads();
    for (int b = threadIdx.x; b < NBK; b += 256)
        C[b * NCHUNK + blk] = hist[b];
}

// wave-per-bucket: exclusive scan of C[r][0..127] in place, row total out
__global__ __launch_bounds__(256) void k_rowscan(int* __restrict__ C,
                                                 int* __restrict__ totals) {
    const int w    = threadIdx.x >> 6;
    const int lane = threadIdx.x & 63;
    const int r    = blockIdx.x * 4 + w;
    if (r >= NBK) return;
    int* row = C + r * NCHUNK;
    const int v0 = row[lane];
    const int v1 = row[64 + lane];
    int s0 = v0, s1 = v1;
#pragma unroll
    for (int off = 1; off < 64; off <<= 1) {
        int y0 = __shfl_up(s0, off);
        int y1 = __shfl_up(s1, off);
        if (lane >= off) { s0 += y0; s1 += y1; }
    }
    s1 += __shfl(s0, 63);          // add first-half total
    row[lane]      = s0 - v0;      // exclusive
    row[64 + lane] = s1 - v1;
    if (lane == 63) totals[r] = s1;
}

// single block: exclusive scan of bucket totals -> bk_ptr; sentinels
__global__ __launch_bounds__(1024) void k_scan_base(const int* __restrict__ totals,
                                                    int* __restrict__ bk_ptr,
                                                    int* __restrict__ row_ptr) {
    __shared__ int sh[1024];
    const int t = threadIdx.x;
    const int v = (t < NBK) ? totals[t] : 0;
    sh[t] = v;
    __syncthreads();
#pragma unroll
    for (int off = 1; off < 1024; off <<= 1) {
        int x = sh[t];
        int a = (t >= off) ? sh[t - off] : 0;
        __syncthreads();
        sh[t] = x + a;
        __syncthreads();
    }
    if (t < NBK) bk_ptr[t] = sh[t] - v;
    if (t == 0) { bk_ptr[NBK] = NE; row_ptr[NN] = NE; }
}

// scatter: LDS cursors = bucket base + this chunk's offset; no global atomics
__global__ __launch_bounds__(256) void k_scatter(const int* __restrict__ src,
                                                 const int* __restrict__ dst,
                                                 const int* __restrict__ C,
                                                 const int* __restrict__ bk_ptr,
                                                 unsigned* __restrict__ ebuf, int e) {
    __shared__ int cur[NBK];
    const int blk = blockIdx.x;
    for (int b = threadIdx.x; b < NBK; b += 256)
        cur[b] = bk_ptr[b] + C[b * NCHUNK + blk];
    __syncthreads();
    const int beg = blk * CH, end = min(beg + CH, e);
    for (int i = beg + threadIdx.x; i < end; i += 256) {
        int d = dst[i];
        int b = d >> BK_SHIFT;
        int pos = atomicAdd(&cur[b], 1);   // LDS atomic, chain ~8
        ebuf[pos] = ((unsigned)(d & 63) << 16) | (unsigned)src[i];  // NN < 65536
    }
}

// one block per bucket: LDS counting-sort by local dst; coalesced outputs
__global__ __launch_bounds__(256) void k_bsort(const unsigned* __restrict__ ebuf,
                                               const int* __restrict__ bk_ptr,
                                               int* __restrict__ row_ptr,
                                               float* __restrict__ dinv,
                                               int* __restrict__ src_sorted, int n) {
    __shared__ unsigned eL[BK_CAP];
    __shared__ int outL[BK_CAP];
    __shared__ int curL[64];
    __shared__ int baseL[64];

    const int b   = blockIdx.x;
    const int beg = bk_ptr[b];
    const int m   = bk_ptr[b + 1] - beg;
    const int t   = threadIdx.x;

    if (t < 64) curL[t] = 0;
    __syncthreads();

    for (int i = t; i < m; i += 256) {
        unsigned v = ebuf[beg + i];
        eL[i] = v;
        atomicAdd(&curL[v >> 16], 1);
    }
    __syncthreads();

    if (t < 64) {
        int c = curL[t];
        int x = c;
#pragma unroll
        for (int off = 1; off < 64; off <<= 1) {
            int y = __shfl_up(x, off);
            if (t >= off) x += y;
        }
        int excl = x - c;
        baseL[t] = excl;
        int d0 = (b << BK_SHIFT) + t;
        if (d0 < n) {
            row_ptr[d0] = beg + excl;
            dinv[d0]    = rsqrtf((float)(c + 1));   // +1 self-loop
        }
    }
    __syncthreads();
    if (t < 64) curL[t] = baseL[t];
    __syncthreads();

    for (int i = t; i < m; i += 256) {
        unsigned v = eL[i];
        int p = atomicAdd(&curL[v >> 16], 1);
        outL[p] = (int)(v & 0xFFFFu);
    }
    __syncthreads();
    for (int i = t; i < m; i += 256) src_sorted[beg + i] = outL[i];
}

// ---------------- dense GEMM: H[n] = bf16( dinv[row] * (X[n] @ W) ) ----------------

template<int DOUT>
__global__ __launch_bounds__(256) void k_gemm(const float* __restrict__ X,
                                              const float* __restrict__ W,
                                              const float* __restrict__ dinv,
                                              __hip_bfloat16* __restrict__ H, int n) {
    constexpr int ROWS = 32;
    constexpr int CPT  = DOUT / 16;
    constexpr int RPT  = 2;

    __shared__ float ws[DI * DOUT];
    __shared__ float xs[ROWS][DI];

    const int tid  = threadIdx.x;
    const int row0 = blockIdx.x * ROWS;

    for (int i = tid; i < DI * DOUT; i += 256) ws[i] = W[i];

    {
        const float4* Xv  = reinterpret_cast<const float4*>(X + (size_t)row0 * DI);
        float4*       xsv = reinterpret_cast<float4*>(&xs[0][0]);
        const int nv   = ROWS * DI / 4;
        const int maxv = ((n - row0) * DI) / 4;
        for (int i = tid; i < nv; i += 256) {
            float4 v = (i < maxv) ? Xv[i] : float4{0.f, 0.f, 0.f, 0.f};
            xsv[i] = v;
        }
    }
    __syncthreads();

    const int cg = tid & 15;
    const int rg = tid >> 4;

    float acc[RPT][CPT];
#pragma unroll
    for (int i = 0; i < RPT; ++i)
#pragma unroll
        for (int j = 0; j < CPT; ++j) acc[i][j] = 0.f;

    for (int k = 0; k < DI; ++k) {
        float xv[RPT];
#pragma unroll
        for (int i = 0; i < RPT; ++i) xv[i] = xs[rg * RPT + i][k];
#pragma unroll
        for (int j = 0; j < CPT; ++j) {
            float wv = ws[k * DOUT + cg * CPT + j];
#pragma unroll
            for (int i = 0; i < RPT; ++i) acc[i][j] += xv[i] * wv;
        }
    }

#pragma unroll
    for (int i = 0; i < RPT; ++i) {
        int row = row0 + rg * RPT + i;
        if (row < n) {
            float dv = dinv[row];
#pragma unroll
            for (int j = 0; j < CPT; ++j)
                H[(size_t)row * DOUT + cg * CPT + j] = __float2bfloat16(acc[i][j] * dv);
        }
    }
}

// ---------------- CSR aggregation over pre-scaled bf16 h' ----------------
// out[d] = dinv[d] * ( h'[d] + sum_{s in N(d)} h'[s] ) + bias ;  h' = dinv*h

template<int D, bool RELU>
__global__ __launch_bounds__(256) void k_agg_csr(const unsigned short* __restrict__ h,
                                                 const float* __restrict__ dinv,
                                                 const int* __restrict__ row_ptr,
                                                 const int* __restrict__ src_sorted,
                                                 const float* __restrict__ bias,
                                                 float* __restrict__ out, int n) {
    constexpr int G = D / 8;
    int t = blockIdx.x * blockDim.x + threadIdx.x;
    if (t >= n * G) return;
    const int node = t / G;
    const int g    = t % G;

    const ushort8* h8 = reinterpret_cast<const ushort8*>(h);

    float accA[8], accB[8];
    {
        ushort8 hv = h8[(size_t)node * G + g];   // self term h'[node]
#pragma unroll
        for (int j = 0; j < 8; ++j) { accA[j] = bf2f(hv[j]); accB[j] = 0.f; }
    }

    const int beg = row_ptr[node];
    const int end = row_ptr[node + 1];
    int k = beg;
    for (; k + 4 <= end; k += 4) {
        int s0 = src_sorted[k + 0];
        int s1 = src_sorted[k + 1];
        int s2 = src_sorted[k + 2];
        int s3 = src_sorted[k + 3];
        ushort8 v0 = h8[(size_t)s0 * G + g];
        ushort8 v1 = h8[(size_t)s1 * G + g];
        ushort8 v2 = h8[(size_t)s2 * G + g];
        ushort8 v3 = h8[(size_t)s3 * G + g];
#pragma unroll
        for (int j = 0; j < 8; ++j) {
            accA[j] += bf2f(v0[j]) + bf2f(v1[j]);
            accB[j] += bf2f(v2[j]) + bf2f(v3[j]);
        }
    }
    for (; k < end; ++k) {
        int s = src_sorted[k];
        ushort8 v = h8[(size_t)s * G + g];
#pragma unroll
        for (int j = 0; j < 8; ++j) accA[j] += bf2f(v[j]);
    }

    const float di = dinv[node];
    const float4* b4 = reinterpret_cast<const float4*>(bias);
    float4 b0 = b4[g * 2], b1 = b4[g * 2 + 1];
    float r[8];
#pragma unroll
    for (int j = 0; j < 8; ++j) r[j] = di * (accA[j] + accB[j]);
    r[0] += b0.x; r[1] += b0.y; r[2] += b0.z; r[3] += b0.w;
    r[4] += b1.x; r[5] += b1.y; r[6] += b1.z; r[7] += b1.w;
    if (RELU) {
#pragma unroll
        for (int j = 0; j < 8; ++j) r[j] = fmaxf(r[j], 0.f);
    }
    float4* o4 = reinterpret_cast<float4*>(out + (size_t)node * D + g * 8);
    o4[0] = float4{r[0], r[1], r[2], r[3]};
    o4[1] = float4{r[4], r[5], r[6], r[7]};
}

// ---------------- launch ----------------

extern "C" void kernel_launch(void* const* d_in, const int* in_sizes, int n_in,
                              void* d_out, int out_size, void* d_ws, size_t ws_size,
                              hipStream_t stream) {
    const float* x   = (const float*)d_in[0];
    const int*   ei  = (const int*)d_in[1];   // [2][NE] int32
    const float* W1  = (const float*)d_in[2];
    const float* b1  = (const float*)d_in[3];
    const float* W2  = (const float*)d_in[4];
    const float* b2  = (const float*)d_in[5];
    float*       out = (float*)d_out;

    const int* srcv = ei;
    const int* dstv = ei + NE;

    // workspace layout (16B alignment for float4/ushort8 arrays)
    char* p = (char*)d_ws;
    float*          dinv  = (float*)p;          p += (size_t)NN * 4;
    float*          a1    = (float*)p;          p += (size_t)NN * DH * 4;
    __hip_bfloat16* h1    = (__hip_bfloat16*)p; p += (size_t)NN * DH * 2;   // reused as h2
    int*      row_ptr     = (int*)p;            p += (size_t)(NN + 1) * 4;
    int*      src_sorted  = (int*)p;            p += (size_t)NE * 4;
    unsigned* ebuf        = (unsigned*)p;       p += (size_t)NE * 4;
    int*      Cm          = (int*)p;            p += (size_t)NBK * NCHUNK * 4;
    int*      totals      = (int*)p;            p += (size_t)NBK * 4;
    int*      bk_ptr      = (int*)p;            p += (size_t)(NBK + 1) * 4;

    const int B = 256;

    // CSR build (no global atomics)
    k_hist<<<NCHUNK, B, 0, stream>>>(dstv, Cm, NE);
    k_rowscan<<<(NBK + 3) / 4, B, 0, stream>>>(Cm, totals);
    k_scan_base<<<1, 1024, 0, stream>>>(totals, bk_ptr, row_ptr);
    k_scatter<<<NCHUNK, B, 0, stream>>>(srcv, dstv, Cm, bk_ptr, ebuf, NE);
    k_bsort<<<NBK, B, 0, stream>>>(ebuf, bk_ptr, row_ptr, dinv, src_sorted, NN);

    // layer 1: h1 = bf16(dinv * (x@W1)) ; a1 = relu(dinv*(self+gather) + b1)
    k_gemm<DH><<<(NN + 31) / 32, B, 0, stream>>>(x, W1, dinv, h1, NN);
    {
        int total = NN * (DH / 8);
        k_agg_csr<DH, true><<<(total + B - 1) / B, B, 0, stream>>>(
            (const unsigned short*)h1, dinv, row_ptr, src_sorted, b1, a1, NN);
    }

    // layer 2
    __hip_bfloat16* h2 = h1;
    k_gemm<DO><<<(NN + 31) / 32, B, 0, stream>>>(a1, W2, dinv, h2, NN);
    {
        int total = NN * (DO / 8);
        k_agg_csr<DO, false><<<(total + B - 1) / B, B, 0, stream>>>(
            (const unsigned short*)h2, dinv, row_ptr, src_sorted, b2, out, NN);
    }
}

// Round 7
// 127.323 us; speedup vs baseline: 2.4278x; 1.0199x over previous
//
#include <hip/hip_runtime.h>
#include <hip/hip_bf16.h>

// GCN: out = GCNConv2( relu( GCNConv1(x) ) )
// Round 6->7: a1 stored bf16 (halves a1 write + gemm2 read traffic);
// k_scan_base folded into k_scatter (each block re-scans 782 totals in LDS,
// block 0 publishes bk_ptr); agg reads src indices via aligned int4.

constexpr int NN = 50000;
constexpr int NE = 800000;
constexpr int DI = 96;
constexpr int DH = 96;
constexpr int DO = 48;

constexpr int BK_SHIFT = 6;                  // 64 dst nodes per bucket
constexpr int NBK      = (NN + 63) >> 6;     // 782 buckets, ~1023 edges each
constexpr int BK_CAP   = 2048;               // >> max bucket load

constexpr int NCHUNK = 128;                  // blocks in hist/scatter
constexpr int CH     = (NE + NCHUNK - 1) / NCHUNK;  // 6250 edges per chunk

typedef unsigned short ushort8 __attribute__((ext_vector_type(8)));

__device__ __forceinline__ float bf2f(unsigned short u) {
    return __uint_as_float(((unsigned int)u) << 16);
}
__device__ __forceinline__ unsigned short f2bf(float f) {
    __hip_bfloat16 b = __float2bfloat16(f);
    return *reinterpret_cast<unsigned short*>(&b);
}

// ---------------- CSR build (atomic-free multisplit) ----------------

// per-chunk LDS histogram -> transposed counts C[bucket][chunk]
__global__ __launch_bounds__(256) void k_hist(const int* __restrict__ dst,
                                              int* __restrict__ C, int e) {
    __shared__ int hist[NBK];
    for (int i = threadIdx.x; i < NBK; i += 256) hist[i] = 0;
    __syncthreads();
    const int blk = blockIdx.x;
    const int beg = blk * CH, end = min(beg + CH, e);
    for (int i = beg + threadIdx.x; i < end; i += 256)
        atomicAdd(&hist[dst[i] >> BK_SHIFT], 1);
    __syncthreads();
    for (int b = threadIdx.x; b < NBK; b += 256)
        C[b * NCHUNK + blk] = hist[b];
}

// wave-per-bucket: exclusive scan of C[r][0..127] in place, row total out
__global__ __launch_bounds__(256) void k_rowscan(int* __restrict__ C,
                                                 int* __restrict__ totals,
                                                 int* __restrict__ row_ptr) {
    if (blockIdx.x == 0 && threadIdx.x == 0) row_ptr[NN] = NE;  // sentinel
    const int w    = threadIdx.x >> 6;
    const int lane = threadIdx.x & 63;
    const int r    = blockIdx.x * 4 + w;
    if (r >= NBK) return;
    int* row = C + r * NCHUNK;
    const int v0 = row[lane];
    const int v1 = row[64 + lane];
    int s0 = v0, s1 = v1;
#pragma unroll
    for (int off = 1; off < 64; off <<= 1) {
        int y0 = __shfl_up(s0, off);
        int y1 = __shfl_up(s1, off);
        if (lane >= off) { s0 += y0; s1 += y1; }
    }
    s1 += __shfl(s0, 63);          // add first-half total
    row[lane]      = s0 - v0;      // exclusive
    row[64 + lane] = s1 - v1;
    if (lane == 63) totals[r] = s1;
}

// scatter: in-LDS scan of totals -> bucket bases; LDS cursors; no global atomics.
// block 0 additionally publishes bk_ptr for k_bsort.
__global__ __launch_bounds__(256) void k_scatter(const int* __restrict__ src,
                                                 const int* __restrict__ dst,
                                                 const int* __restrict__ C,
                                                 const int* __restrict__ totals,
                                                 int* __restrict__ bk_ptr,
                                                 unsigned* __restrict__ ebuf, int e) {
    __shared__ int bkL[NBK + 1];
    __shared__ int part[256];
    __shared__ int cur[NBK];
    const int t = threadIdx.x;

    // blocked load + scan of 782 totals
    int v[4];
    int s = 0;
    const int base = t * 4;
#pragma unroll
    for (int i = 0; i < 4; ++i) {
        int idx = base + i;
        v[i] = (idx < NBK) ? totals[idx] : 0;
        s += v[i];
    }
    part[t] = s;
    __syncthreads();
#pragma unroll
    for (int off = 1; off < 256; off <<= 1) {
        int x = part[t];
        int a = (t >= off) ? part[t - off] : 0;
        __syncthreads();
        part[t] = x + a;
        __syncthreads();
    }
    int run = part[t] - s;             // exclusive prefix of this thread's 4-chunk
#pragma unroll
    for (int i = 0; i < 4; ++i) {
        int idx = base + i;
        if (idx <= NBK) bkL[idx] = run;
        run += v[i];
    }
    __syncthreads();

    const int blk = blockIdx.x;
    for (int b = t; b < NBK; b += 256) cur[b] = bkL[b] + C[b * NCHUNK + blk];
    if (blk == 0)
        for (int i = t; i <= NBK; i += 256) bk_ptr[i] = bkL[i];
    __syncthreads();

    const int beg = blk * CH, end = min(beg + CH, e);
    for (int i = beg + t; i < end; i += 256) {
        int d = dst[i];
        int b = d >> BK_SHIFT;
        int pos = atomicAdd(&cur[b], 1);   // LDS atomic, chain ~8
        ebuf[pos] = ((unsigned)(d & 63) << 16) | (unsigned)src[i];  // NN < 65536
    }
}

// one block per bucket: LDS counting-sort by local dst; coalesced outputs
__global__ __launch_bounds__(256) void k_bsort(const unsigned* __restrict__ ebuf,
                                               const int* __restrict__ bk_ptr,
                                               int* __restrict__ row_ptr,
                                               float* __restrict__ dinv,
                                               int* __restrict__ src_sorted, int n) {
    __shared__ unsigned eL[BK_CAP];
    __shared__ int outL[BK_CAP];
    __shared__ int curL[64];
    __shared__ int baseL[64];

    const int b   = blockIdx.x;
    const int beg = bk_ptr[b];
    const int m   = bk_ptr[b + 1] - beg;
    const int t   = threadIdx.x;

    if (t < 64) curL[t] = 0;
    __syncthreads();

    for (int i = t; i < m; i += 256) {
        unsigned v = ebuf[beg + i];
        eL[i] = v;
        atomicAdd(&curL[v >> 16], 1);
    }
    __syncthreads();

    if (t < 64) {
        int c = curL[t];
        int x = c;
#pragma unroll
        for (int off = 1; off < 64; off <<= 1) {
            int y = __shfl_up(x, off);
            if (t >= off) x += y;
        }
        int excl = x - c;
        baseL[t] = excl;
        int d0 = (b << BK_SHIFT) + t;
        if (d0 < n) {
            row_ptr[d0] = beg + excl;
            dinv[d0]    = rsqrtf((float)(c + 1));   // +1 self-loop
        }
    }
    __syncthreads();
    if (t < 64) curL[t] = baseL[t];
    __syncthreads();

    for (int i = t; i < m; i += 256) {
        unsigned v = eL[i];
        int p = atomicAdd(&curL[v >> 16], 1);
        outL[p] = (int)(v & 0xFFFFu);
    }
    __syncthreads();
    for (int i = t; i < m; i += 256) src_sorted[beg + i] = outL[i];
}

// ---------------- dense GEMM: H[n] = bf16( dinv[row] * (X[n] @ W) ) ----------------
// XBF16: input matrix stored bf16 (a1), else f32 (x).

template<int DOUT, bool XBF16>
__global__ __launch_bounds__(256) void k_gemm(const void* __restrict__ Xin,
                                              const float* __restrict__ W,
                                              const float* __restrict__ dinv,
                                              unsigned short* __restrict__ H, int n) {
    constexpr int ROWS = 32;
    constexpr int CPT  = DOUT / 16;
    constexpr int RPT  = 2;

    __shared__ float ws[DI * DOUT];
    __shared__ unsigned char xraw[ROWS * DI * (XBF16 ? 2 : 4)];
    float*          xsf = reinterpret_cast<float*>(xraw);
    unsigned short* xsu = reinterpret_cast<unsigned short*>(xraw);

    const int tid  = threadIdx.x;
    const int row0 = blockIdx.x * ROWS;

    for (int i = tid; i < DI * DOUT; i += 256) ws[i] = W[i];

    if (XBF16) {
        const ushort8* Xv = reinterpret_cast<const ushort8*>(
            (const unsigned short*)Xin + (size_t)row0 * DI);
        ushort8* xv = reinterpret_cast<ushort8*>(xsu);
        const int nv   = ROWS * DI / 8;                 // 384
        const int maxv = ((n - row0) * DI) / 8;
        for (int i = tid; i < nv; i += 256)
            xv[i] = (i < maxv) ? Xv[i] : (ushort8)(0);
    } else {
        const float4* Xv = reinterpret_cast<const float4*>(
            (const float*)Xin + (size_t)row0 * DI);
        float4* xv = reinterpret_cast<float4*>(xsf);
        const int nv   = ROWS * DI / 4;                 // 768
        const int maxv = ((n - row0) * DI) / 4;
        for (int i = tid; i < nv; i += 256)
            xv[i] = (i < maxv) ? Xv[i] : float4{0.f, 0.f, 0.f, 0.f};
    }
    __syncthreads();

    const int cg = tid & 15;
    const int rg = tid >> 4;

    float acc[RPT][CPT];
#pragma unroll
    for (int i = 0; i < RPT; ++i)
#pragma unroll
        for (int j = 0; j < CPT; ++j) acc[i][j] = 0.f;

    for (int k = 0; k < DI; ++k) {
        float xv[RPT];
#pragma unroll
        for (int i = 0; i < RPT; ++i) {
            int r = rg * RPT + i;
            xv[i] = XBF16 ? bf2f(xsu[r * DI + k]) : xsf[r * DI + k];
        }
#pragma unroll
        for (int j = 0; j < CPT; ++j) {
            float wv = ws[k * DOUT + cg * CPT + j];
#pragma unroll
            for (int i = 0; i < RPT; ++i) acc[i][j] += xv[i] * wv;
        }
    }

#pragma unroll
    for (int i = 0; i < RPT; ++i) {
        int row = row0 + rg * RPT + i;
        if (row < n) {
            float dv = dinv[row];
#pragma unroll
            for (int j = 0; j < CPT; ++j)
                H[(size_t)row * DOUT + cg * CPT + j] = f2bf(acc[i][j] * dv);
        }
    }
}

// ---------------- CSR aggregation over pre-scaled bf16 h' ----------------
// out[d] = dinv[d] * ( h'[d] + sum_{s in N(d)} h'[s] ) + bias ;  h' = dinv*h
// OUTBF16: write bf16 (a1 path) else f32 (final out).

template<int D, bool RELU, bool OUTBF16>
__global__ __launch_bounds__(256) void k_agg_csr(const unsigned short* __restrict__ h,
                                                 const float* __restrict__ dinv,
                                                 const int* __restrict__ row_ptr,
                                                 const int* __restrict__ src_sorted,
                                                 const float* __restrict__ bias,
                                                 void* __restrict__ outp, int n) {
    constexpr int G = D / 8;
    int t = blockIdx.x * blockDim.x + threadIdx.x;
    if (t >= n * G) return;
    const int node = t / G;
    const int g    = t % G;

    const ushort8* h8 = reinterpret_cast<const ushort8*>(h);

    float accA[8], accB[8];
    {
        ushort8 hv = h8[(size_t)node * G + g];   // self term h'[node]
#pragma unroll
        for (int j = 0; j < 8; ++j) { accA[j] = bf2f(hv[j]); accB[j] = 0.f; }
    }

    const int beg = row_ptr[node];
    const int end = row_ptr[node + 1];
    int k = beg;
    // scalar head up to 4-alignment
    int kA = min((beg + 3) & ~3, end);
    for (; k < kA; ++k) {
        int s = src_sorted[k];
        ushort8 vv = h8[(size_t)s * G + g];
#pragma unroll
        for (int j = 0; j < 8; ++j) accA[j] += bf2f(vv[j]);
    }
    // aligned int4 main loop, 4 gathers in flight
    const int4* sv = reinterpret_cast<const int4*>(src_sorted + k);
    for (; k + 4 <= end; k += 4) {
        int4 s4 = *sv++;
        ushort8 v0 = h8[(size_t)s4.x * G + g];
        ushort8 v1 = h8[(size_t)s4.y * G + g];
        ushort8 v2 = h8[(size_t)s4.z * G + g];
        ushort8 v3 = h8[(size_t)s4.w * G + g];
#pragma unroll
        for (int j = 0; j < 8; ++j) {
            accA[j] += bf2f(v0[j]) + bf2f(v1[j]);
            accB[j] += bf2f(v2[j]) + bf2f(v3[j]);
        }
    }
    for (; k < end; ++k) {
        int s = src_sorted[k];
        ushort8 vv = h8[(size_t)s * G + g];
#pragma unroll
        for (int j = 0; j < 8; ++j) accA[j] += bf2f(vv[j]);
    }

    const float di = dinv[node];
    const float4* b4 = reinterpret_cast<const float4*>(bias);
    float4 b0 = b4[g * 2], b1 = b4[g * 2 + 1];
    float r[8];
#pragma unroll
    for (int j = 0; j < 8; ++j) r[j] = di * (accA[j] + accB[j]);
    r[0] += b0.x; r[1] += b0.y; r[2] += b0.z; r[3] += b0.w;
    r[4] += b1.x; r[5] += b1.y; r[6] += b1.z; r[7] += b1.w;
    if (RELU) {
#pragma unroll
        for (int j = 0; j < 8; ++j) r[j] = fmaxf(r[j], 0.f);
    }
    if (OUTBF16) {
        ushort8 o;
#pragma unroll
        for (int j = 0; j < 8; ++j) o[j] = f2bf(r[j]);
        reinterpret_cast<ushort8*>((unsigned short*)outp)[(size_t)node * G + g] = o;
    } else {
        float4* o4 = reinterpret_cast<float4*>((float*)outp + (size_t)node * D + g * 8);
        o4[0] = float4{r[0], r[1], r[2], r[3]};
        o4[1] = float4{r[4], r[5], r[6], r[7]};
    }
}

// ---------------- launch ----------------

extern "C" void kernel_launch(void* const* d_in, const int* in_sizes, int n_in,
                              void* d_out, int out_size, void* d_ws, size_t ws_size,
                              hipStream_t stream) {
    const float* x   = (const float*)d_in[0];
    const int*   ei  = (const int*)d_in[1];   // [2][NE] int32
    const float* W1  = (const float*)d_in[2];
    const float* b1  = (const float*)d_in[3];
    const float* W2  = (const float*)d_in[4];
    const float* b2  = (const float*)d_in[5];
    float*       out = (float*)d_out;

    const int* srcv = ei;
    const int* dstv = ei + NE;

    // workspace layout (16B alignment for vector arrays)
    char* p = (char*)d_ws;
    float*          dinv  = (float*)p;           p += (size_t)NN * 4;
    unsigned short* a1    = (unsigned short*)p;  p += (size_t)NN * DH * 2;   // bf16
    unsigned short* h1    = (unsigned short*)p;  p += (size_t)NN * DH * 2;   // bf16, reused as h2
    int*      row_ptr     = (int*)p;             p += (size_t)(NN + 16) * 4;
    int*      src_sorted  = (int*)p;             p += (size_t)NE * 4;
    unsigned* ebuf        = (unsigned*)p;        p += (size_t)NE * 4;
    int*      Cm          = (int*)p;             p += (size_t)NBK * NCHUNK * 4;
    int*      totals      = (int*)p;             p += (size_t)NBK * 4;
    int*      bk_ptr      = (int*)p;             p += (size_t)(NBK + 1) * 4;

    const int B = 256;

    // CSR build (no global atomics)
    k_hist<<<NCHUNK, B, 0, stream>>>(dstv, Cm, NE);
    k_rowscan<<<(NBK + 3) / 4, B, 0, stream>>>(Cm, totals, row_ptr);
    k_scatter<<<NCHUNK, B, 0, stream>>>(srcv, dstv, Cm, totals, bk_ptr, ebuf, NE);
    k_bsort<<<NBK, B, 0, stream>>>(ebuf, bk_ptr, row_ptr, dinv, src_sorted, NN);

    // layer 1: h1 = bf16(dinv * (x@W1)) ; a1 = bf16(relu(dinv*(self+gather) + b1))
    k_gemm<DH, false><<<(NN + 31) / 32, B, 0, stream>>>(x, W1, dinv, h1, NN);
    {
        int total = NN * (DH / 8);
        k_agg_csr<DH, true, true><<<(total + B - 1) / B, B, 0, stream>>>(
            h1, dinv, row_ptr, src_sorted, b1, a1, NN);
    }

    // layer 2: h2 = bf16(dinv * (a1@W2)) ; out = dinv*(self+gather) + b2
    unsigned short* h2 = h1;
    k_gemm<DO, true><<<(NN + 31) / 32, B, 0, stream>>>(a1, W2, dinv, h2, NN);
    {
        int total = NN * (DO / 8);
        k_agg_csr<DO, false, false><<<(total + B - 1) / B, B, 0, stream>>>(
            h2, dinv, row_ptr, src_sorted, b2, out, NN);
    }
}